// Round 7
// baseline (486.019 us; speedup 1.0000x reference)
//
#include <hip/hip_runtime.h>
#include <math.h>

#define T_ 256
#define B_ 128
#define D_ 1024
#define K_ 21
#define NBLK 43  // ceil(B_/3): one block per batch-triple, fwd+vit+producers
#define MAGIC64 0xA3C59B17E4D2F861ull

typedef short v8s __attribute__((ext_vector_type(8)));
typedef float v4f __attribute__((ext_vector_type(4)));

__device__ __forceinline__ short bf16rne(float f) {
  unsigned u = __float_as_uint(f);
  u += 0x7FFFu + ((u >> 16) & 1u);  // round-nearest-even
  return (short)(u >> 16);
}
__device__ __forceinline__ float rdl(float v, int l) {
  return __int_as_float(__builtin_amdgcn_readlane(__float_as_int(v), l));
}
__device__ __forceinline__ int imax3(int a, int b, int c) {
  const int t = a > b ? a : b;  // fuses to v_max3_i32
  return t > c ? t : c;
}
__device__ __forceinline__ int cvt2(float lo, float hi) {  // 2xf32 -> packed bf16
  int r;
  asm("v_cvt_pk_bf16_f32 %0, %1, %2" : "=v"(r) : "v"(lo), "v"(hi));
  return r;
}
__device__ __forceinline__ void lds_wait(int* f) {
  while (__hip_atomic_load(f, __ATOMIC_RELAXED, __HIP_MEMORY_SCOPE_WORKGROUP) == 0)
    __builtin_amdgcn_s_sleep(1);
}
__device__ __forceinline__ void lds_set(int* f) {
  __hip_atomic_store(f, 1, __ATOMIC_RELAXED, __HIP_MEMORY_SCOPE_WORKGROUP);
}

// ---------------------------------------------------------------------------
// Single kernel, 43 blocks x 256 threads (1 block/CU; LDS ~108 KB).
// Per block (batch triple b0..b0+2):
//   wave 0: forward/denominator scan (round-3 loop, unchanged)
//   wave 1: Viterbi scan (round-3 loop, unchanged)
//   waves 2,3: producers — MFMA fc chunks (32 t-rows x 3 b x 21 tags,
//     K=1024, W staged once in LDS as bf16) straight into the fcs LDS
//     double buffer; wave 2 also computes the numerator from the LDS chunk.
// Sync: per-chunk LDS flags. Producer's ds_writes precede its flag write in
// the in-order DS queue => consumer that observes the flag sees the data
// (single CU-coherent LDS; no fences). Back-pressure: producers wait for
// both consumers + numerator to finish chunk c-2 before overwriting.
// fc never goes to global memory; the fc kernel, its launch gap, and the
// numerator's global fc reads are all eliminated. Round-5's failure mode
// (per-chunk agent fences, cross-XCD L2 maintenance) does not apply:
// the only device-scope sync is one loss-gate at the end.
// ---------------------------------------------------------------------------
__global__ __launch_bounds__(256) void crf_kernel(
    const float* __restrict__ A, const float* __restrict__ W,
    const float* __restrict__ bias, const int* __restrict__ tags,
    const float* __restrict__ startT, const float* __restrict__ endT,
    const float* __restrict__ trans, float* __restrict__ out_tags,
    float* __restrict__ out_loss, unsigned long long* __restrict__ readyg) {
  __shared__ float fcs[2][32][64];         // fc chunk double buffer, 16 KB
  __shared__ unsigned short Wt[21 * 1032]; // W^T bf16, row-padded, 43.3 KB
  __shared__ unsigned short bp[256 * 66];  // bp[t][g][tag], 33.8 KB
  __shared__ unsigned char h2[127 * 66];   // tag@2v <- tag@(2v+2)
  __shared__ unsigned char h4[63 * 66];    // tag@4w <- tag@(4w+4)
  __shared__ unsigned char cur[3 * 256];
  __shared__ float stateF[3 * 24], stateV[3 * 24];  // 21 + pad per group
  __shared__ int flg[5][8];  // [0]=ready w2, [1]=ready w3, [2]=consF, [3]=consV, [4]=consN

  const int tix = threadIdx.x;
  const int lane = tix & 63;
  const int wv = tix >> 6;
  const int blk = blockIdx.x;
  const int b0 = blk * 3;

  if (tix < 40) ((int*)flg)[tix] = 0;
  if (blk == 0 && tix == 0) {
    atomicExch(out_loss, 0.f);  // device-scope; gate below orders the adds
    __builtin_amdgcn_fence(__ATOMIC_RELEASE, "agent");
    __hip_atomic_store(readyg, MAGIC64, __ATOMIC_RELAXED,
                       __HIP_MEMORY_SCOPE_AGENT);
  }
  // stage W^T as bf16: Wt[c][k] = bf16(W[k][c]); coalesced read of W.
  for (int i = tix; i < K_ * D_; i += 256) {
    const int k = i / K_, c = i - (i / K_) * K_;
    Wt[c * 1032 + k] = (unsigned short)bf16rne(W[i]);
  }

  // lengths (every wave computes the same values via its own ballots)
  int len0 = 0, len1 = 0, len2 = 0;
#pragma unroll
  for (int q = 0; q < 4; ++q) {
    const int t = q * 64 + lane;
    int bb0 = b0, bb1 = b0 + 1, bb2 = b0 + 2;
    if (bb1 >= B_) bb1 = B_ - 1;
    if (bb2 >= B_) bb2 = B_ - 1;
    len0 += __popcll(__ballot(tags[t * B_ + bb0] != 0));
    len1 += __popcll(__ballot(tags[t * B_ + bb1] != 0));
    len2 += __popcll(__ballot(tags[t * B_ + bb2] != 0));
  }
  __syncthreads();  // flags zeroed + Wt staged

  int g = lane / 21;
  if (g > 2) g = 2;
  int jloc = lane - g * 21;
  if (jloc > 20) jloc = 20;
  const int gj = g * 21 + jloc;  // lane 63 duplicates lane 62
  const int mylen = (g == 0) ? len0 : (g == 1) ? len1 : len2;
  int last0 = 0, last1 = 0, last2 = 0;  // set by vit wave, used in backtrace

  if (wv == 0) {
    // ================= forward / denominator (linear domain) ==============
    float* sb = stateF + g * 24;
    const v4f* sv = (const v4f*)sb;
    float ec[21];
#pragma unroll
    for (int i = 0; i < K_; ++i) ec[i] = __expf(trans[i * K_ + jloc]);
    float p = 0.f, L = 0.f;

    for (int c = 0; c < 8; ++c) {
      lds_wait(&flg[0][c]);
      lds_wait(&flg[1][c]);
      const float* fb = &fcs[c & 1][0][0];
      int t0 = c * 32;
      if (c == 0) {
        p = __expf(startT[jloc] + fb[gj]);
        sb[jloc] = p;
        t0 = 1;
      }
      const int t1 = c * 32 + 32;
      for (int t = t0; t < t1; ++t) {
        const float emt = fb[(t & 31) * 64 + gj];
        const v4f A0 = sv[0], A1 = sv[1], A2 = sv[2], A3 = sv[3], A4 = sv[4];
        const float A5 = sb[20];

        float d0 = A0[0] * ec[0], d1 = A0[1] * ec[1], d2 = A0[2] * ec[2];
        d0 = fmaf(A0[3], ec[3], d0); d1 = fmaf(A1[0], ec[4], d1);
        d2 = fmaf(A1[1], ec[5], d2);
        d0 = fmaf(A1[2], ec[6], d0); d1 = fmaf(A1[3], ec[7], d1);
        d2 = fmaf(A2[0], ec[8], d2);
        d0 = fmaf(A2[1], ec[9], d0); d1 = fmaf(A2[2], ec[10], d1);
        d2 = fmaf(A2[3], ec[11], d2);
        d0 = fmaf(A3[0], ec[12], d0); d1 = fmaf(A3[1], ec[13], d1);
        d2 = fmaf(A3[2], ec[14], d2);
        d0 = fmaf(A3[3], ec[15], d0); d1 = fmaf(A4[0], ec[16], d1);
        d2 = fmaf(A4[1], ec[17], d2);
        d0 = fmaf(A4[2], ec[18], d0); d1 = fmaf(A4[3], ec[19], d1);
        d2 = fmaf(A5, ec[20], d2);

        const float pn = ((d0 + d1) + d2) * __expf(emt);
        p = (t < mylen) ? pn : p;
        if ((t & 7) == 0) {  // group-uniform renorm by OLD p[0] (in regs)
          const float f = A0[0];
          p *= __builtin_amdgcn_rcpf(f);
          L += __logf(f);
        }
        sb[jloc] = p;
      }
      lds_set(&flg[2][c]);
    }

    const float w = p * __expf(endT[jloc]);
    float res = 0.f;
#pragma unroll
    for (int gg = 0; gg < 3; ++gg) {
      if (b0 + gg < B_) {
        float tot = 0.f;
#pragma unroll
        for (int i = 0; i < K_; ++i) tot += rdl(w, gg * K_ + i);
        res += rdl(L, gg * K_) + __logf(tot);
      }
    }
    if (lane == 0) {
      while (__hip_atomic_load(readyg, __ATOMIC_RELAXED,
                               __HIP_MEMORY_SCOPE_AGENT) != MAGIC64)
        __builtin_amdgcn_s_sleep(4);
      __builtin_amdgcn_fence(__ATOMIC_ACQUIRE, "agent");
      atomicAdd(out_loss, res);  // +den
    }
  } else if (wv == 1) {
    // ================= Viterbi ============================================
    float* sb = stateV + g * 24;
    const v4f* sv = (const v4f*)sb;
    float tr[21];
#pragma unroll
    for (int i = 0; i < K_; ++i) tr[i] = trans[i * K_ + jloc] + 2048.0f;
    float sc = 0.f;

    for (int c = 0; c < 8; ++c) {
      lds_wait(&flg[0][c]);
      lds_wait(&flg[1][c]);
      const float* fb = &fcs[c & 1][0][0];
      int t0 = c * 32;
      if (c == 0) {
        sc = startT[jloc] + fb[gj];
        sb[jloc] = sc;
        t0 = 1;
      }
      const int t1 = c * 32 + 32;
      for (int t = t0; t < t1; ++t) {
        const float emt = fb[(t & 31) * 64 + gj];
        const v4f A0 = sv[0], A1 = sv[1], A2 = sv[2], A3 = sv[3], A4 = sv[4];
        const float A5 = sb[20];

        // key = (bits & ~31) | (20-i): larger key <=> smaller prev tag
        // (first-argmax). All keys positive (score+2048 > 0).
#define KEY(i, V) ((__float_as_int((V) + tr[i]) & 0xFFFFFFE0) | (20 - (i)))
        const int q0 = imax3(KEY(0, A0[0]), KEY(1, A0[1]), KEY(2, A0[2]));
        const int q1 = imax3(KEY(3, A0[3]), KEY(4, A1[0]), KEY(5, A1[1]));
        const int q2 = imax3(KEY(6, A1[2]), KEY(7, A1[3]), KEY(8, A2[0]));
        const int q3 = imax3(KEY(9, A2[1]), KEY(10, A2[2]), KEY(11, A2[3]));
        const int q4 = imax3(KEY(12, A3[0]), KEY(13, A3[1]), KEY(14, A3[2]));
        const int q5 = imax3(KEY(15, A3[3]), KEY(16, A4[0]), KEY(17, A4[1]));
        const int q6 = imax3(KEY(18, A4[2]), KEY(19, A4[3]), KEY(20, A5));
        const int km = imax3(imax3(q0, q1, q2), imax3(q3, q4, q5), q6);
#undef KEY
        const float nxt = __int_as_float(km & 0xFFFFFFE0) - 2048.0f + emt;
        const bool m = t < mylen;
        sc = m ? nxt : sc;
        sb[jloc] = sc;
        const int pw = m ? (20 - (km & 31)) : jloc;  // identity when frozen
        bp[t * 66 + g * 22 + jloc] = (unsigned short)pw;  // lane63 dups 62
      }
      lds_set(&flg[3][c]);
    }

    // final argmax per group (tie-break: smallest tag)
    const float finb = sc + endT[jloc] + 2048.0f;
    const int myk = (__float_as_int(finb) & 0xFFFFFFE0) | (20 - jloc);
#pragma unroll
    for (int gg = 0; gg < 3; ++gg) {
      int km = 0;
#pragma unroll
      for (int i = 0; i < K_; ++i) {
        const int ki = __builtin_amdgcn_readlane(myk, gg * K_ + i);
        km = km > ki ? km : ki;
      }
      const int lt = 20 - (km & 31);
      if (gg == 0) last0 = lt;
      else if (gg == 1) last1 = lt;
      else last2 = lt;
    }
  } else {
    // ================= producers (waves 2,3): fc chunks + numerator =======
    const int wid = wv - 2;
    const int m15 = lane & 15, g4 = lane >> 4;
    const float bias0 = bias[m15];
    const float bias1 = (m15 < 5) ? bias[16 + m15] : 0.f;
    // M-tiles: rows r = g*32 + t_loc (96 rows); tile mt: g = mt>>1,
    // t_loc = (mt&1)*16 + row_in_tile. wave2: mt 0-2, wave3: mt 3-5.
    int ggm[3], tbase[3];
    size_t abase[3];
#pragma unroll
    for (int m = 0; m < 3; ++m) {
      const int mt = 3 * wid + m;
      ggm[m] = mt >> 1;
      tbase[m] = (mt & 1) * 16;
      int bb = b0 + ggm[m];
      if (bb >= B_) bb = B_ - 1;
      abase[m] = ((size_t)(tbase[m] + m15) * B_ + bb) * D_ + 8 * g4;
    }
    float numacc = 0.f;

    for (int c = 0; c < 8; ++c) {
      if (c >= 2) {  // back-pressure: both consumers + numerator done c-2
        lds_wait(&flg[2][c - 2]);
        lds_wait(&flg[3][c - 2]);
        lds_wait(&flg[4][c - 2]);
      }
      v4f acc[3][2];
#pragma unroll
      for (int m = 0; m < 3; ++m) {
        acc[m][0] = (v4f)(0.f);
        acc[m][1] = (v4f)(0.f);
      }
      const size_t coff = (size_t)c * 32 * B_ * D_;
#pragma unroll 2
      for (int ks = 0; ks < 32; ++ks) {
        const int wo = 32 * ks + 8 * g4;
        const v8s bf0 = *(const v8s*)&Wt[m15 * 1032 + wo];
        v8s bf1;
        if (m15 < 5) {
          bf1 = *(const v8s*)&Wt[(16 + m15) * 1032 + wo];
        } else {
#pragma unroll
          for (int j = 0; j < 8; ++j) bf1[j] = 0;
        }
#pragma unroll
        for (int m = 0; m < 3; ++m) {
          const float* Ap = A + abase[m] + coff + 32 * ks;
          const float4 x = *(const float4*)Ap;
          const float4 y = *(const float4*)(Ap + 4);
          union { int4 i4; v8s s8; } u;
          u.i4.x = cvt2(x.x, x.y);
          u.i4.y = cvt2(x.z, x.w);
          u.i4.z = cvt2(y.x, y.y);
          u.i4.w = cvt2(y.z, y.w);
          acc[m][0] = __builtin_amdgcn_mfma_f32_16x16x32_bf16(u.s8, bf0,
                                                              acc[m][0], 0, 0, 0);
          acc[m][1] = __builtin_amdgcn_mfma_f32_16x16x32_bf16(u.s8, bf1,
                                                              acc[m][1], 0, 0, 0);
        }
      }
      // D store: lane holds rows 4*g4+ri of the tile, col m15 (+16 tile1)
      float* fb = &fcs[c & 1][0][0];
#pragma unroll
      for (int m = 0; m < 3; ++m) {
        const int cb = ggm[m] * 21;
#pragma unroll
        for (int ri = 0; ri < 4; ++ri) {
          const int tl = tbase[m] + 4 * g4 + ri;
          fb[tl * 64 + cb + m15] = acc[m][0][ri] + bias0;
          if (m15 < 5) fb[tl * 64 + cb + 16 + m15] = acc[m][1][ri] + bias1;
        }
      }
      lds_set(&flg[wid][c]);  // ds-writes precede flag in in-order queue

      if (wid == 0) {  // numerator from the completed LDS chunk
        lds_wait(&flg[1][c]);
        if (lane < 32) {
          const int t = c * 32 + lane;
#pragma unroll
          for (int gg = 0; gg < 3; ++gg) {
            const int bb = b0 + gg;
            if (bb < B_) {
              const int tg = tags[t * B_ + bb];
              if (t == 0) {
                numacc += startT[tg] + fb[gg * 21 + tg];
              } else if (tg != 0) {
                const int pg = tags[(t - 1) * B_ + bb];
                numacc += trans[pg * K_ + tg] + fb[(t & 31) * 64 + gg * 21 + tg];
              }
              if (tg != 0 && (t == T_ - 1 || tags[(t + 1) * B_ + bb] == 0))
                numacc += endT[tg];
            }
          }
        }
        lds_set(&flg[4][c]);
      }
    }
    if (wid == 0) {
#pragma unroll
      for (int off = 32; off > 0; off >>= 1)
        numacc += __shfl_down(numacc, off, 64);
      if (lane == 0) {
        while (__hip_atomic_load(readyg, __ATOMIC_RELAXED,
                                 __HIP_MEMORY_SCOPE_AGENT) != MAGIC64)
          __builtin_amdgcn_s_sleep(4);
        __builtin_amdgcn_fence(__ATOMIC_ACQUIRE, "agent");
        atomicAdd(out_loss, -numacc);  // -num
      }
    }
  }

  // ================= backtrace (all 256 threads) ==========================
  __syncthreads();  // bp + last* complete
  for (int i = tix; i < 127 * 63; i += 256) {
    const int v = i / 63;
    const int rem = i - v * 63;
    const int gg = rem / 21, j = rem - (rem / 21) * 21;
    h2[v * 66 + gg * 22 + j] = (unsigned char)
        bp[(2 * v + 1) * 66 + gg * 22 + bp[(2 * v + 2) * 66 + gg * 22 + j]];
  }
  __syncthreads();
  for (int i = tix; i < 63 * 63; i += 256) {
    const int w2 = i / 63;
    const int rem = i - w2 * 63;
    const int gg = rem / 21, j = rem - (rem / 21) * 21;
    h4[w2 * 66 + gg * 22 + j] =
        h2[(2 * w2) * 66 + gg * 22 + h2[(2 * w2 + 1) * 66 + gg * 22 + j]];
  }
  __syncthreads();

  // 3 parallel serial chases (vit wave lanes 0..2 hold last0..2)
  if (wv == 1 && lane < 3 && b0 + lane < B_) {
    int c = (lane == 0) ? last0 : (lane == 1) ? last1 : last2;
    cur[lane * 256 + 255] = (unsigned char)c;
    c = bp[255 * 66 + lane * 22 + c];
    cur[lane * 256 + 254] = (unsigned char)c;
    c = h2[126 * 66 + lane * 22 + c];
    cur[lane * 256 + 252] = (unsigned char)c;
    for (int w2 = 62; w2 >= 0; --w2) {
      c = h4[w2 * 66 + lane * 22 + c];
      cur[lane * 256 + 4 * w2] = (unsigned char)c;
    }
  }
  __syncthreads();
  for (int i = tix; i < 63 * 3; i += 256) {  // t = 2 mod 4
    const int gg = i / 63, ii = i - (i / 63) * 63;
    const int t = 2 + 4 * ii;
    cur[gg * 256 + t] = h2[(t >> 1) * 66 + gg * 22 + cur[gg * 256 + t + 2]];
  }
  __syncthreads();
  for (int i = tix; i < 127 * 3; i += 256) {  // odd t
    const int gg = i / 127, ii = i - (i / 127) * 127;
    const int t = 1 + 2 * ii;
    cur[gg * 256 + t] =
        (unsigned char)bp[(t + 1) * 66 + gg * 22 + cur[gg * 256 + t + 1]];
  }
  __syncthreads();
  for (int i = tix; i < 3 * 256; i += 256) {
    const int gg = i >> 8, t = i & 255;
    const int bb = b0 + gg;
    const int lg = (gg == 0) ? len0 : (gg == 1) ? len1 : len2;
    if (bb < B_)
      out_tags[t * B_ + bb] = (t < lg) ? (float)cur[gg * 256 + t] : 0.f;
  }
}

extern "C" void kernel_launch(void* const* d_in, const int* in_sizes, int n_in,
                              void* d_out, int out_size, void* d_ws,
                              size_t ws_size, hipStream_t stream) {
  const float* A = (const float*)d_in[0];
  const int* tags = (const int*)d_in[1];
  const float* W = (const float*)d_in[2];
  const float* bias = (const float*)d_in[3];
  const float* startT = (const float*)d_in[4];
  const float* endT = (const float*)d_in[5];
  const float* trans = (const float*)d_in[6];

  float* out_tags = (float*)d_out;
  float* out_loss = (float*)d_out + (size_t)T_ * B_;
  unsigned long long* readyg = (unsigned long long*)d_ws;  // loss-gate flag

  crf_kernel<<<NBLK, 256, 0, stream>>>(A, W, bias, tags, startT, endT, trans,
                                       out_tags, out_loss, readyg);
}

// Round 8
// 273.472 us; speedup vs baseline: 1.7772x; 1.7772x over previous
//
#include <hip/hip_runtime.h>
#include <math.h>

#define T_ 256
#define B_ 128
#define D_ 1024
#define K_ 21
#define NB3 43  // ceil(B_/3) wave-blocks for each scan flavor

typedef short v8s __attribute__((ext_vector_type(8)));
typedef float v4f __attribute__((ext_vector_type(4)));

__device__ __forceinline__ short bf16rne(float f) {
  unsigned u = __float_as_uint(f);
  u += 0x7FFFu + ((u >> 16) & 1u);  // round-nearest-even
  return (short)(u >> 16);
}
__device__ __forceinline__ float rdl(float v, int l) {
  return __int_as_float(__builtin_amdgcn_readlane(__float_as_int(v), l));
}
__device__ __forceinline__ int imax3(int a, int b, int c) {
  const int t = a > b ? a : b;  // fuses to v_max3_i32
  return t > c ? t : c;
}

// ---------------------------------------------------------------------------
// Kernel 1: FC as bf16 MFMA GEMM (proven round-3 version). Block = 256 thr
// (4 waves); wave wv owns k-chunk [wv*256,+256) for rows [bid*64,+64).
// Block 0 zeroes out_loss (no separate memset dispatch).
// Structural note: A (134 MB) must be read by the FULL chip — per-CU HBM
// streaming is ~24 GB/s, so any scheme concentrating A-reads into few
// blocks is >=130 us (round-7 failure). Keep this kernel full-grid.
// ---------------------------------------------------------------------------
__global__ __launch_bounds__(256) void fc_kernel(
    const float* __restrict__ A, const float* __restrict__ W,
    const float* __restrict__ bias, float* __restrict__ fc,
    float* __restrict__ out_loss) {
  __shared__ float red[3][64][22];
  if (blockIdx.x == 0 && threadIdx.x == 0) *out_loss = 0.f;
  const int lane = threadIdx.x & 63;
  const int wv = threadIdx.x >> 6;
  const int m15 = lane & 15, g4 = lane >> 4;
  const int rowbase = blockIdx.x * 64;
  const int kc = wv * 256;
  const int n1 = 16 + m15;

  v8s bf[8][2];
#pragma unroll
  for (int s = 0; s < 8; ++s) {
    const float* Wp = W + (size_t)(kc + 32 * s + 8 * g4) * K_;
#pragma unroll
    for (int j = 0; j < 8; ++j) bf[s][0][j] = bf16rne(Wp[j * K_ + m15]);
    if (n1 < K_) {
#pragma unroll
      for (int j = 0; j < 8; ++j) bf[s][1][j] = bf16rne(Wp[j * K_ + n1]);
    } else {
#pragma unroll
      for (int j = 0; j < 8; ++j) bf[s][1][j] = 0;
    }
  }

  v4f acc[4][2];
#pragma unroll
  for (int m = 0; m < 4; ++m) {
    acc[m][0] = (v4f)(0.f);
    acc[m][1] = (v4f)(0.f);
  }

#pragma unroll
  for (int s = 0; s < 8; ++s) {
    v8s av[4];
#pragma unroll
    for (int m = 0; m < 4; ++m) {
      const float* Ap =
          A + (size_t)(rowbase + 16 * m + m15) * D_ + kc + 32 * s + 8 * g4;
      const float4 x = *(const float4*)Ap;
      const float4 y = *(const float4*)(Ap + 4);
      av[m][0] = bf16rne(x.x); av[m][1] = bf16rne(x.y);
      av[m][2] = bf16rne(x.z); av[m][3] = bf16rne(x.w);
      av[m][4] = bf16rne(y.x); av[m][5] = bf16rne(y.y);
      av[m][6] = bf16rne(y.z); av[m][7] = bf16rne(y.w);
    }
#pragma unroll
    for (int m = 0; m < 4; ++m) {
      acc[m][0] = __builtin_amdgcn_mfma_f32_16x16x32_bf16(av[m], bf[s][0],
                                                          acc[m][0], 0, 0, 0);
      acc[m][1] = __builtin_amdgcn_mfma_f32_16x16x32_bf16(av[m], bf[s][1],
                                                          acc[m][1], 0, 0, 0);
    }
  }

  if (wv > 0) {
#pragma unroll
    for (int m = 0; m < 4; ++m)
#pragma unroll
      for (int ri = 0; ri < 4; ++ri) {
        const int rl = 16 * m + 4 * g4 + ri;
        red[wv - 1][rl][m15] = acc[m][0][ri];
        if (n1 < K_) red[wv - 1][rl][n1] = acc[m][1][ri];
      }
  }
  __syncthreads();
  if (wv == 0) {
    const float b0 = bias[m15];
    const float b1 = (n1 < K_) ? bias[n1] : 0.f;
#pragma unroll
    for (int m = 0; m < 4; ++m)
#pragma unroll
      for (int ri = 0; ri < 4; ++ri) {
        const int rl = 16 * m + 4 * g4 + ri;
        float* o = fc + (size_t)(rowbase + rl) * K_;
        o[m15] = acc[m][0][ri] + red[0][rl][m15] + red[1][rl][m15] +
                 red[2][rl][m15] + b0;
        if (n1 < K_)
          o[n1] = acc[m][1][ri] + red[0][rl][n1] + red[1][rl][n1] +
                  red[2][rl][n1] + b1;
      }
  }
}

// ---------------------------------------------------------------------------
// Kernel 2: sequential scans (round-2 v3 structure — the 277.8 us best).
// 3 batches per wave, lane = g*21 + jloc. Per-step all-gather through an
// LDS state vector (1 ds_write_b32 + 5 ds_read_b128 + 1 ds_read_b32,
// per-wave in-order => no barrier). Emissions prefetched distance-4 via a
// rotating 4-register pipeline (static rotation, manually unrolled x4).
// v8 deltas vs round 2: vit max tree as v_max3_i32 triples; fwd renorm
// every 16 steps (exponent <= e^58, safe); unguarded bp store (lane 63 is
// a bit-identical duplicate of lane 62).
// Blocks [0,43): forward; [43,86): Viterbi; [86,214): numerator.
// ---------------------------------------------------------------------------
__global__ __launch_bounds__(64) void scan_kernel(
    const float* __restrict__ fc, const int* __restrict__ tags,
    const float* __restrict__ startT, const float* __restrict__ endT,
    const float* __restrict__ trans, float* __restrict__ out_tags,
    float* __restrict__ out_loss) {
  __shared__ unsigned short bp[256 * 66];  // bp[t][g][tag], stride 66/22
  __shared__ unsigned char h2[127 * 66];   // tag@2v   <- tag@(2v+2)
  __shared__ unsigned char h4[63 * 66];    // tag@4w   <- tag@(4w+4)
  __shared__ unsigned char cur[3 * 256];
  __shared__ v4f statev[18];               // 3 groups x 24 floats (21 + pad)

  const int lane = threadIdx.x;
  const int blk = blockIdx.x;

  if (blk < 2 * NB3) {
    const bool fwd = blk < NB3;
    const int bblk = fwd ? blk : blk - NB3;
    int g = lane / 21;
    if (g > 2) g = 2;
    int jloc = lane - g * 21;
    if (jloc > 20) jloc = 20;
    int batch = bblk * 3 + g;
    if (batch >= B_) batch = B_ - 1;

    // lengths per group (uniform, via ballots); mask[t] == (t < len)
    int len0 = 0, len1 = 0, len2 = 0;
#pragma unroll
    for (int q = 0; q < 4; ++q) {
      const int t = q * 64 + lane;
      int b0 = bblk * 3, b1 = bblk * 3 + 1, b2 = bblk * 3 + 2;
      if (b1 >= B_) b1 = B_ - 1;
      if (b2 >= B_) b2 = B_ - 1;
      len0 += __popcll(__ballot(tags[t * B_ + b0] != 0));
      len1 += __popcll(__ballot(tags[t * B_ + b1] != 0));
      len2 += __popcll(__ballot(tags[t * B_ + b2] != 0));
    }
    const int mylen = (g == 0) ? len0 : (g == 1) ? len1 : len2;

    float* sb = (float*)statev + g * 24;   // this group's state (21 floats)
    const v4f* sv = (const v4f*)sb;        // 16B-aligned (24 floats = 96B)

#define FCAT(t) fc[((size_t)(t) * B_ + batch) * K_ + jloc]
    const float em0 = FCAT(0);

    if (fwd) {
      // ---------------- forward / denominator (linear domain) ------------
      float ec[21];  // exp(trans[:, jloc]) straight (no rotation)
#pragma unroll
      for (int i = 0; i < K_; ++i) ec[i] = __expf(trans[i * K_ + jloc]);
      float p = __expf(startT[jloc] + em0);
      sb[jloc] = p;  // lane 63 duplicates lane 62's write (same value)
      float L = 0.f;
      // rotating emission pipeline: entering iter t, slots = fc[t+1..t+4],
      // ee = exp(fc[t]).
      float sA = FCAT(2), sB = FCAT(3), sC = FCAT(4), sD = FCAT(5);
      float ee = __expf(FCAT(1));

#define FWD_STEP(t, RA, RB, RC, RD)                                          \
      {                                                                      \
        const v4f A0 = sv[0], A1 = sv[1], A2 = sv[2], A3 = sv[3],            \
                  A4 = sv[4];                                                \
        const float A5 = sb[20];                                             \
        const float eet = ee;                                                \
        ee = __expf(RA); /* RA = fc[t+1], loaded 4 iters ago */              \
        {                                                                    \
          const int tn = ((t) + 5 < T_) ? (t) + 5 : T_ - 1;                  \
          RA = FCAT(tn); /* refill consumed slot */                          \
        }                                                                    \
        float d0 = A0[0] * ec[0], d1 = A0[1] * ec[1], d2 = A0[2] * ec[2];    \
        d0 = fmaf(A0[3], ec[3], d0); d1 = fmaf(A1[0], ec[4], d1);            \
        d2 = fmaf(A1[1], ec[5], d2);                                         \
        d0 = fmaf(A1[2], ec[6], d0); d1 = fmaf(A1[3], ec[7], d1);            \
        d2 = fmaf(A2[0], ec[8], d2);                                         \
        d0 = fmaf(A2[1], ec[9], d0); d1 = fmaf(A2[2], ec[10], d1);           \
        d2 = fmaf(A2[3], ec[11], d2);                                        \
        d0 = fmaf(A3[0], ec[12], d0); d1 = fmaf(A3[1], ec[13], d1);          \
        d2 = fmaf(A3[2], ec[14], d2);                                        \
        d0 = fmaf(A3[3], ec[15], d0); d1 = fmaf(A4[0], ec[16], d1);          \
        d2 = fmaf(A4[1], ec[17], d2);                                        \
        d0 = fmaf(A4[2], ec[18], d0); d1 = fmaf(A4[3], ec[19], d1);          \
        d2 = fmaf(A5, ec[20], d2);                                           \
        const float pn = ((d0 + d1) + d2) * eet;                             \
        p = ((t) < mylen) ? pn : p;                                          \
        if (((t) & 15) == 0) {                                               \
          /* group-uniform renorm by OLD p[0] (in registers); exponent   */  \
          /* growth over 16 steps <= ~e^58 < f32 max                     */  \
          const float f = A0[0];                                             \
          p *= __builtin_amdgcn_rcpf(f);                                     \
          L += __logf(f);                                                    \
        }                                                                    \
        sb[jloc] = p; /* state for step t+1 */                               \
      }

      for (int t = 1; t + 3 <= 252; t += 4) {
        FWD_STEP(t + 0, sA, sB, sC, sD)
        FWD_STEP(t + 1, sB, sC, sD, sA)
        FWD_STEP(t + 2, sC, sD, sA, sB)
        FWD_STEP(t + 3, sD, sA, sB, sC)
      }
      FWD_STEP(253, sA, sB, sC, sD)
      FWD_STEP(254, sB, sC, sD, sA)
      FWD_STEP(255, sC, sD, sA, sB)
#undef FWD_STEP

      const float w = p * __expf(endT[jloc]);
      float res = 0.f;
#pragma unroll
      for (int gg = 0; gg < 3; ++gg) {
        if (bblk * 3 + gg < B_) {
          float tot = 0.f;
#pragma unroll
          for (int i = 0; i < K_; ++i) tot += rdl(w, gg * K_ + i);
          res += rdl(L, gg * K_) + __logf(tot);
        }
      }
      if (lane == 0) atomicAdd(out_loss, res);  // +den
    } else {
      // ---------------- Viterbi ----------------
      float tr[21];  // trans[:, jloc] + 2048 straight (no rotation)
#pragma unroll
      for (int i = 0; i < K_; ++i) tr[i] = trans[i * K_ + jloc] + 2048.0f;
      float sc = startT[jloc] + em0;
      sb[jloc] = sc;
      // rotating emission pipeline: entering iter t, slots = fc[t..t+3]
      float sA = FCAT(1), sB = FCAT(2), sC = FCAT(3), sD = FCAT(4);

      // key = (bits & ~31) | (20-i): larger key <=> smaller prev tag on
      // ties (matches jnp.argmax first-max). All keys positive
      // (score + 2048 > 0).
#define KEY(i, V) ((__float_as_int((V) + tr[i]) & 0xFFFFFFE0) | (20 - (i)))
#define VIT_STEP(t, RA, RB, RC, RD)                                          \
      {                                                                      \
        const v4f A0 = sv[0], A1 = sv[1], A2 = sv[2], A3 = sv[3],            \
                  A4 = sv[4];                                                \
        const float A5 = sb[20];                                             \
        const float emt = RA; /* fc[t], loaded 4 iters ago */                \
        {                                                                    \
          const int tn = ((t) + 4 < T_) ? (t) + 4 : T_ - 1;                  \
          RA = FCAT(tn);                                                     \
        }                                                                    \
        const int q0 = imax3(KEY(0, A0[0]), KEY(1, A0[1]), KEY(2, A0[2]));   \
        const int q1 = imax3(KEY(3, A0[3]), KEY(4, A1[0]), KEY(5, A1[1]));   \
        const int q2 = imax3(KEY(6, A1[2]), KEY(7, A1[3]), KEY(8, A2[0]));   \
        const int q3 = imax3(KEY(9, A2[1]), KEY(10, A2[2]), KEY(11, A2[3])); \
        const int q4 = imax3(KEY(12, A3[0]), KEY(13, A3[1]),                 \
                             KEY(14, A3[2]));                                \
        const int q5 = imax3(KEY(15, A3[3]), KEY(16, A4[0]),                 \
                             KEY(17, A4[1]));                                \
        const int q6 = imax3(KEY(18, A4[2]), KEY(19, A4[3]), KEY(20, A5));   \
        const int km = imax3(imax3(q0, q1, q2), imax3(q3, q4, q5), q6);      \
        const float nxt = __int_as_float(km & 0xFFFFFFE0) - 2048.0f + emt;   \
        const bool m = (t) < mylen;                                          \
        sc = m ? nxt : sc;                                                   \
        sb[jloc] = sc; /* state for step t+1 */                              \
        const int pw = m ? (20 - (km & 31)) : jloc;                          \
        bp[(t) * 66 + g * 22 + jloc] = (unsigned short)pw;                   \
      }

      for (int t = 1; t + 3 <= 252; t += 4) {
        VIT_STEP(t + 0, sA, sB, sC, sD)
        VIT_STEP(t + 1, sB, sC, sD, sA)
        VIT_STEP(t + 2, sC, sD, sA, sB)
        VIT_STEP(t + 3, sD, sA, sB, sC)
      }
      VIT_STEP(253, sA, sB, sC, sD)
      VIT_STEP(254, sB, sC, sD, sA)
      VIT_STEP(255, sC, sD, sA, sB)
#undef VIT_STEP
#undef KEY
      __syncthreads();

      // final argmax per group (tie-break: smallest tag)
      const float finb = sc + endT[jloc] + 2048.0f;
      const int myk = (__float_as_int(finb) & 0xFFFFFFE0) | (20 - jloc);
      int last0 = 0, last1 = 0, last2 = 0;
#pragma unroll
      for (int gg = 0; gg < 3; ++gg) {
        int km = 0;
#pragma unroll
        for (int i = 0; i < K_; ++i) {
          const int ki = __builtin_amdgcn_readlane(myk, gg * K_ + i);
          km = km > ki ? km : ki;
        }
        const int lt = 20 - (km & 31);
        if (gg == 0) last0 = lt;
        else if (gg == 1) last1 = lt;
        else last2 = lt;
      }

      // skip tables (parallel over lanes)
      for (int i = lane; i < 127 * 63; i += 64) {
        const int v = i / 63;
        const int rem = i - v * 63;
        const int gg = rem / 21, j = rem - (rem / 21) * 21;
        h2[v * 66 + gg * 22 + j] = (unsigned char)
            bp[(2 * v + 1) * 66 + gg * 22 + bp[(2 * v + 2) * 66 + gg * 22 + j]];
      }
      __syncthreads();
      for (int i = lane; i < 63 * 63; i += 64) {
        const int w2 = i / 63;
        const int rem = i - w2 * 63;
        const int gg = rem / 21, j = rem - (rem / 21) * 21;
        h4[w2 * 66 + gg * 22 + j] =
            h2[(2 * w2) * 66 + gg * 22 + h2[(2 * w2 + 1) * 66 + gg * 22 + j]];
      }
      __syncthreads();

      // 3 parallel serial chases (lane == group)
      if (lane < 3 && bblk * 3 + lane < B_) {
        int c = (lane == 0) ? last0 : (lane == 1) ? last1 : last2;
        cur[lane * 256 + 255] = (unsigned char)c;
        c = bp[255 * 66 + lane * 22 + c];
        cur[lane * 256 + 254] = (unsigned char)c;
        c = h2[126 * 66 + lane * 22 + c];
        cur[lane * 256 + 252] = (unsigned char)c;
        for (int w2 = 62; w2 >= 0; --w2) {
          c = h4[w2 * 66 + lane * 22 + c];
          cur[lane * 256 + 4 * w2] = (unsigned char)c;
        }
      }
      __syncthreads();
      for (int i = lane; i < 63 * 3; i += 64) {  // t = 2 mod 4
        const int gg = i / 63, ii = i - (i / 63) * 63;
        const int t = 2 + 4 * ii;
        cur[gg * 256 + t] =
            h2[(t >> 1) * 66 + gg * 22 + cur[gg * 256 + t + 2]];
      }
      __syncthreads();
      for (int i = lane; i < 127 * 3; i += 64) {  // odd t
        const int gg = i / 127, ii = i - (i / 127) * 127;
        const int t = 1 + 2 * ii;
        cur[gg * 256 + t] = (unsigned char)
            bp[(t + 1) * 66 + gg * 22 + cur[gg * 256 + t + 1]];
      }
      __syncthreads();
      for (int i = lane; i < 3 * 256; i += 64) {
        const int gg = i >> 8, t = i & 255;
        const int bb = bblk * 3 + gg;
        const int lg = (gg == 0) ? len0 : (gg == 1) ? len1 : len2;
        if (bb < B_)
          out_tags[t * B_ + bb] = (t < lg) ? (float)cur[gg * 256 + t] : 0.f;
      }
    }
#undef FCAT
  } else {
    // ---------------- numerator ----------------
    const int b = blk - 2 * NB3;
    float contrib = 0.f;
#pragma unroll
    for (int q = 0; q < 4; ++q) {
      const int t = lane * 4 + q;
      const int tg = tags[t * B_ + b];
      const size_t ro = ((size_t)t * B_ + b) * K_;
      if (t == 0) {
        contrib += startT[tg] + fc[ro + tg];
      } else if (tg != 0) {
        const int pg = tags[(t - 1) * B_ + b];
        contrib += trans[pg * K_ + tg] + fc[ro + tg];
      }
      const bool isLast =
          (tg != 0) && (t == T_ - 1 || tags[(t + 1) * B_ + b] == 0);
      if (isLast) contrib += endT[tg];
    }
#pragma unroll
    for (int off = 32; off > 0; off >>= 1)
      contrib += __shfl_down(contrib, off, 64);
    if (lane == 0) atomicAdd(out_loss, -contrib);  // -num
  }
}

extern "C" void kernel_launch(void* const* d_in, const int* in_sizes, int n_in,
                              void* d_out, int out_size, void* d_ws,
                              size_t ws_size, hipStream_t stream) {
  const float* A = (const float*)d_in[0];
  const int* tags = (const int*)d_in[1];
  const float* W = (const float*)d_in[2];
  const float* bias = (const float*)d_in[3];
  const float* startT = (const float*)d_in[4];
  const float* endT = (const float*)d_in[5];
  const float* trans = (const float*)d_in[6];

  float* out_tags = (float*)d_out;
  float* out_loss = (float*)d_out + (size_t)T_ * B_;
  float* fc = (float*)d_ws;  // [t*B+b][21] f32, 2.75 MB

  fc_kernel<<<512, 256, 0, stream>>>(A, W, bias, fc, out_loss);
  scan_kernel<<<2 * NB3 + B_, 64, 0, stream>>>(fc, tags, startT, endT, trans,
                                               out_tags, out_loss);
}